// Round 20
// baseline (255.084 us; speedup 1.0000x reference)
//
#include <hip/hip_runtime.h>
#include <hip/hip_bf16.h>
#include <math.h>

#define B_ 4
#define N_ 8192
#define MD_ 512
#define H_ 8
#define F_ 16
#define S_ 32
#define S3_ 32768
#define L_ 256
#define CO_ 152   // H*(F+3)
#define HF_ 128   // H*F
#define EPS_ 1e-5f
#define CHUNK_ 1024
#define PS_ 34            // padded lattice dim
#define PS2_ 1156         // 34*34
#define PV_ 39304         // 34^3 voxels per (b,h)
#define HALO_ 6536        // 34^3 - 32^3
#define INVN_ (1.f / 8192.f)

typedef __attribute__((ext_vector_type(8))) short bf16x8;
typedef __attribute__((ext_vector_type(4))) float f32x4;

__device__ inline unsigned short f2bf(float f) {   // RNE fp32 -> bf16
    unsigned u = __float_as_uint(f);
    return (unsigned short)((u + 0x7FFFu + ((u >> 16) & 1u)) >> 16);
}

// ---- fused setup: zeros + style_proj + conv-w + wconvert + halo (no LDS) ---
__global__ __launch_bounds__(256) void setup_misc(
    const float* __restrict__ style,
    const float* __restrict__ kw_w, const float* __restrict__ kw_b,
    const float* __restrict__ vw_w, const float* __restrict__ vw_b,
    const float* __restrict__ aw_w, const float* __restrict__ aw_b,
    const float* __restrict__ cw, const float* __restrict__ Wkv,
    float* __restrict__ hk, float* __restrict__ hv, float* __restrict__ ha,
    unsigned short* __restrict__ wb, unsigned short* __restrict__ wkb,
    int* __restrict__ counts, int* __restrict__ cursor,
    float* __restrict__ sums, unsigned short* __restrict__ zb16p) {
    int blk = blockIdx.x;
    int tid = threadIdx.x;
    if (blk == 0) {                       // zero counters/cursors/stat sums
        #pragma unroll
        for (int q = 0; q < 4; ++q) counts[q * 256 + tid] = 0;
        #pragma unroll
        for (int q = 0; q < 4; ++q) cursor[q * 256 + tid] = 0;
        for (int i = tid; i < 2240; i += 256) sums[i] = 0.f;
    } else if (blk < 5) {                 // style projections (4 blocks)
        int b = blk - 1;
        const float* st = style + b * L_;
        for (int r = tid; r < 48 + 256 + 256; r += 256) {
            const float* wrow; float bias; float* dst; int j;
            if (r < 48)       { j = r;       wrow = kw_w + j * L_; bias = kw_b[j]; dst = hk + b * 48; }
            else if (r < 304) { j = r - 48;  wrow = vw_w + j * L_; bias = vw_b[j]; dst = hv + b * 256; }
            else              { j = r - 304; wrow = aw_w + j * L_; bias = aw_b[j]; dst = ha + b * 256; }
            float acc = bias;
            for (int l = 0; l < L_; ++l) acc = fmaf(st[l], wrow[l], acc);
            dst[j] = acc;
        }
    } else if (blk < 245) {               // conv weights, 61440 total
        int i = (blk - 5) * 256 + tid;
        if (i < 61440) {
            int ic = i & 15;
            int oc = (i >> 4) & 15;
            int s  = (i >> 8) % 30;
            int h  = (i >> 8) / 30;
            int p = s >> 1, tsel = s & 1;
            int pair = p % 5, dy = p / 5;
            int c = (pair < 4) ? (pair * 2 + tsel) : 8;
            bool zero = (pair == 4) && (tsel == 1);
            int tap = (c / 3) * 9 + dy * 3 + (c % 3);
            float v = zero ? 0.f : cw[(((h * 16 + oc) * 16 + ic) * 27) + tap];
            wb[i] = f2bf(v);
        }
    } else if (blk < 285) {               // W_kv -> bf16 frags [mt][kc][r16][k8]
        int i = (blk - 245) * 256 + tid;  // 10240 total
        if (i < 10240) {
            int r  = i & 15;
            int kc = (i >> 4) & 63;
            int mt = i >> 10;
            int row = mt * 16 + r;
            unsigned int pk[4];
            #pragma unroll
            for (int j = 0; j < 4; ++j) {
                float v0 = (row < CO_) ? Wkv[(size_t)row * MD_ + kc * 8 + 2 * j] : 0.f;
                float v1 = (row < CO_) ? Wkv[(size_t)row * MD_ + kc * 8 + 2 * j + 1] : 0.f;
                pk[j] = (unsigned)f2bf(v0) | ((unsigned)f2bf(v1) << 16);
            }
            *(uint4*)(wkb + (((size_t)(mt * 64 + kc)) * 16 + r) * 8) =
                make_uint4(pk[0], pk[1], pk[2], pk[3]);
        }
    } else {                              // halo zeroing: 817 blocks, 209152 = 32*HALO
        int i = (blk - 285) * 256 + tid;
        int bh = i / HALO_;
        int j  = i - bh * HALO_;
        int x, y, z;
        if (j < 2312) {
            x = (j / 1156) * 33;
            int rem = j % 1156;
            y = rem / 34; z = rem % 34;
        } else {
            int k = j - 2312;
            x = 1 + k / 132;
            int m = k % 132;
            if (m < 34)       { y = 0;  z = m; }
            else if (m < 68)  { y = 33; z = m - 34; }
            else if (m < 100) { y = m - 68 + 1;  z = 0; }
            else              { y = m - 100 + 1; z = 33; }
        }
        int pv = (x * PS_ + y) * PS_ + z;
        unsigned short* p = zb16p + ((size_t)bh * PV_ + pv) * 16;
        ((uint4*)p)[0] = make_uint4(0, 0, 0, 0);
        ((uint4*)p)[1] = make_uint4(0, 0, 0, 0);
    }
}

// ---- kv = W_kv @ input via bf16 MFMA, fp32 input staged through LDS --------
// grid (64 nblocks x B); block = 4 waves x 32 cols (2 n-tiles), all 152 rows.
// Per K-step (32 ch): cooperative stage fp32->bf16 frags in LDS, then MFMA.
__global__ __launch_bounds__(256) void kv_gemm_fused(
    const float* __restrict__ X, const unsigned short* __restrict__ wkb,
    float* __restrict__ kv, float* __restrict__ kvsum, float* __restrict__ kvsq) {
    __shared__ unsigned short s_xt[4096];   // [nt(8)][kcl(4)][n16(16)][k8(8)] bf16
    unsigned* s32 = (unsigned*)s_xt;
    int b = blockIdx.y;
    int n0 = blockIdx.x * 128;
    int tid = threadIdx.x;
    int lane = tid & 63, w = tid >> 6;
    int rc = lane & 15, kg = lane >> 4;
    int q = tid >> 4, nq = tid & 15;       // staging role: 2 channels x 8 n
    const float* xb0 = X + (size_t)b * MD_ * N_ + n0 + nq * 8;
    int snt = nq >> 1;
    int kcl = q >> 2, kq = q & 3;
    int sbase = ((snt * 4 + kcl) * 16 + ((nq & 1) * 8)) * 4 + kq;

    f32x4 acc[10][2];
    #pragma unroll
    for (int mt = 0; mt < 10; ++mt)
        #pragma unroll
        for (int j = 0; j < 2; ++j) acc[mt][j] = (f32x4){0.f, 0.f, 0.f, 0.f};

    #pragma unroll 1
    for (int ks = 0; ks < 16; ++ks) {
        const float* xr = xb0 + (size_t)(ks * 32 + 2 * q) * N_;
        float4 a0 = *(const float4*)(xr);
        float4 a1 = *(const float4*)(xr + 4);
        float4 b0 = *(const float4*)(xr + N_);
        float4 b1 = *(const float4*)(xr + N_ + 4);
        float av[8] = {a0.x, a0.y, a0.z, a0.w, a1.x, a1.y, a1.z, a1.w};
        float bv[8] = {b0.x, b0.y, b0.z, b0.w, b1.x, b1.y, b1.z, b1.w};
        #pragma unroll
        for (int i = 0; i < 8; ++i)
            s32[sbase + i * 4] = (unsigned)f2bf(av[i]) | ((unsigned)f2bf(bv[i]) << 16);
        __syncthreads();
        #pragma unroll
        for (int j = 0; j < 2; ++j) {
            bf16x8 bf = *(const bf16x8*)(s_xt + (((w * 2 + j) * 4 + kg) * 16 + rc) * 8);
            #pragma unroll
            for (int mt = 0; mt < 10; ++mt) {
                bf16x8 af = *(const bf16x8*)(wkb + (((size_t)(mt * 64 + ks * 4 + kg)) * 16 + rc) * 8);
                acc[mt][j] = __builtin_amdgcn_mfma_f32_16x16x32_bf16(af, bf, acc[mt][j], 0, 0, 0);
            }
        }
        __syncthreads();
    }
    // epilogue: C-write + fused channel stats
    #pragma unroll
    for (int mt = 0; mt < 10; ++mt) {
        #pragma unroll
        for (int j = 0; j < 2; ++j) {
            int col = n0 + w * 32 + j * 16 + rc;
            #pragma unroll
            for (int r = 0; r < 4; ++r) {
                int m = mt * 16 + kg * 4 + r;
                if (m < CO_) kv[((size_t)b * CO_ + m) * N_ + col] = acc[mt][j][r];
            }
        }
        #pragma unroll
        for (int r = 0; r < 4; ++r) {
            int m = mt * 16 + kg * 4 + r;
            float v0 = acc[mt][0][r], v1 = acc[mt][1][r];
            float s = v0 + v1;
            float qq = fmaf(v0, v0, v1 * v1);
            #pragma unroll
            for (int off = 1; off < 16; off <<= 1) {
                s  += __shfl_xor(s, off);
                qq += __shfl_xor(qq, off);
            }
            if (rc == 0 && m < CO_) {
                atomicAdd(&kvsum[b * CO_ + m], s);
                atomicAdd(&kvsq[b * CO_ + m], qq);
            }
        }
    }
}

// ---------------- point prep: AdaIN (stats from sums) + transform + interp --
__global__ __launch_bounds__(256) void point_prep(
    const float* __restrict__ kv, const float* __restrict__ kvsum,
    const float* __restrict__ kvsq, const float* __restrict__ hk,
    const float* __restrict__ hv, const float* __restrict__ orig,
    const float* __restrict__ scale_p, const float* __restrict__ Tw,
    const float* __restrict__ Tb,
    float4* __restrict__ coordbuf, unsigned* __restrict__ vbuf16,
    int* __restrict__ counts) {
    __shared__ int s_hist[32];
    int tid = threadIdx.x;
    if (tid < 32) s_hist[tid] = 0;
    __syncthreads();
    int p = blockIdx.x * 256 + tid;
    int n = p & (N_ - 1);
    int bh = p >> 13;               // uniform per block
    int h = bh & 7, b = bh >> 3;
    float scl = scale_p[0];

    float pt[3];
    #pragma unroll
    for (int j = 0; j < 3; ++j) {
        int bc = b * CO_ + h * 3 + j;
        float mu = kvsum[bc] * INVN_;
        float rs = rsqrtf(kvsq[bc] * INVN_ - mu * mu + EPS_);
        float x  = kv[(size_t)bc * N_ + n];
        float xn = (x - mu) * rs;
        float kr = fmaf(1.f + hk[b * 48 + h * 3 + j], xn, hk[b * 48 + 24 + h * 3 + j]);
        pt[j] = fmaf(scl, kr, orig[((size_t)(b * 3 + j)) * N_ + n]);
    }
    int f0[3]; float tt[3];
    #pragma unroll
    for (int i = 0; i < 3; ++i) {
        float key = Tb[h * 3 + i];
        #pragma unroll
        for (int j = 0; j < 3; ++j) key = fmaf(Tw[(h * 3 + i) * 3 + j], pt[j], key);
        float lat = tanhf(key);
        float g = (lat + 1.f) * 0.5f * (float)(S_ - 1);
        float ff = floorf(g);
        ff = fminf(fmaxf(ff, 0.f), 30.f);
        f0[i] = (int)ff;
        tt[i] = fminf(fmaxf(g - ff, 0.f), 1.f);
    }
    coordbuf[p] = make_float4(tt[0], tt[1], tt[2],
                              __int_as_float(f0[0] | (f0[1] << 5) | (f0[2] << 10)));
    atomicAdd(&s_hist[f0[0]], 1);   // LDS
    float vf[16];
    #pragma unroll
    for (int f = 0; f < F_; ++f) {
        int bc = b * CO_ + 24 + h * F_ + f;
        float mu = kvsum[bc] * INVN_;
        float rs = rsqrtf(kvsq[bc] * INVN_ - mu * mu + EPS_);
        float x  = kv[(size_t)bc * N_ + n];
        float xn = (x - mu) * rs;
        int cv = h * F_ + f;
        vf[f] = fmaf(1.f + hv[b * 256 + cv], xn, hv[b * 256 + 128 + cv]);
    }
    unsigned pk2[8];
    #pragma unroll
    for (int q = 0; q < 8; ++q)
        pk2[q] = (unsigned)f2bf(vf[2 * q]) | ((unsigned)f2bf(vf[2 * q + 1]) << 16);
    uint4* vb = (uint4*)(vbuf16 + (size_t)p * 8);
    vb[0] = make_uint4(pk2[0], pk2[1], pk2[2], pk2[3]);
    vb[1] = make_uint4(pk2[4], pk2[5], pk2[6], pk2[7]);
    __syncthreads();
    if (tid < 32 && s_hist[tid] > 0)
        atomicAdd(&counts[(bh << 5) + tid], s_hist[tid]);
}

// ---------------- scatter: local prefix over counts + LDS-aggregated claim --
__global__ __launch_bounds__(256) void scatter_pts(
    const float4* __restrict__ coordbuf, const int* __restrict__ counts,
    int* __restrict__ cursor, unsigned short* __restrict__ recs) {
    __shared__ int s_hist[32];
    __shared__ int s_dst[32];
    int tid = threadIdx.x;
    if (tid < 32) s_hist[tid] = 0;
    __syncthreads();
    int p = blockIdx.x * 256 + tid;
    int bh = p >> 13;               // uniform per block
    int pk = __float_as_int(((const float*)coordbuf)[(size_t)p * 4 + 3]);
    int f0x = pk & 31;
    int rank = atomicAdd(&s_hist[f0x], 1);   // LDS
    __syncthreads();
    if (tid < 32) {
        int cnt = counts[(bh << 5) + tid];
        int incl = cnt;
        #pragma unroll
        for (int off = 1; off < 32; off <<= 1) {
            int u = __shfl_up(incl, off);
            if (tid >= off) incl += u;
        }
        int bse = (bh << 13) + incl - cnt;   // bh*8192 + exclusive prefix
        if (s_hist[tid] > 0)
            s_dst[tid] = bse + atomicAdd(&cursor[(bh << 5) + tid], s_hist[tid]);
    }
    __syncthreads();
    recs[s_dst[f0x] + rank] = (unsigned short)(p & (N_ - 1));
}

// ---------------- splat3 v3: CHUNK 1024, single-wave prefix, 5 barriers -----
__global__ __launch_bounds__(1024) void splat3(
    const float4* __restrict__ coordbuf, const unsigned* __restrict__ vbuf16,
    const int* __restrict__ counts, const unsigned short* __restrict__ recs,
    unsigned short* __restrict__ zb16p) {
    __shared__ int s_cnt[1024];
    __shared__ int s_start[1024];
    __shared__ int s_cur[1024];
    __shared__ unsigned s_rec[CHUNK_ * 12];   // 48KB sorted records
    __shared__ int s_binbase[33];
    int logical = (blockIdx.x & 7) * 128 + (blockIdx.x >> 3);  // XCD swizzle
    int bh = logical >> 5;
    int x0 = logical & 31;
    int tid = threadIdx.x;
    int y = tid >> 5, zc = tid & 31;
    if (tid < 32) {
        int cnt = counts[(bh << 5) + tid];
        int incl = cnt;
        #pragma unroll
        for (int off = 1; off < 32; off <<= 1) {
            int u = __shfl_up(incl, off);
            if (tid >= off) incl += u;
        }
        s_binbase[tid + 1] = incl;
        if (tid == 0) s_binbase[0] = 0;
    }
    __syncthreads();
    int s0 = (bh << 13) + s_binbase[x0];
    int len0 = s_binbase[x0 + 1] - s_binbase[x0];
    int s1 = 0, len1 = 0;
    if (x0 > 0) { s1 = (bh << 13) + s_binbase[x0 - 1]; len1 = s_binbase[x0] - s_binbase[x0 - 1]; }
    int total = len0 + len1;
    const float4* cb = coordbuf + (size_t)bh * N_;
    const unsigned* vb = vbuf16 + ((size_t)bh * N_) * 8;
    float acc[16];
    #pragma unroll
    for (int i = 0; i < 16; ++i) acc[i] = 0.f;

    for (int c0 = 0; c0 < total; c0 += CHUNK_) {
        int cl = min(CHUNK_, total - c0);
        s_cnt[tid] = 0;
        __syncthreads();                              // B1
        int n = 0, cx = 0, sb = 0;
        float4 c;
        bool active = (tid < cl);
        if (active) {
            int tp = c0 + tid;
            if (tp < len0) { n = recs[s0 + tp]; cx = 0; }
            else           { n = recs[s1 + (tp - len0)]; cx = 1; }
            c = cb[n];
            int pk = __float_as_int(c.w);
            sb = (((pk >> 5) & 31) << 5) | ((pk >> 10) & 31);
            atomicAdd(&s_cnt[sb], 1);
        }
        __syncthreads();                              // B2
        if (tid < 64) {                               // one wave scans all 1024 bins
            int bse = tid * 16;
            int loc[16], sum = 0;
            #pragma unroll
            for (int i2 = 0; i2 < 16; ++i2) { loc[i2] = sum; sum += s_cnt[bse + i2]; }
            int incl = sum;
            #pragma unroll
            for (int off = 1; off < 64; off <<= 1) {
                int u = __shfl_up(incl, off);
                if (tid >= off) incl += u;
            }
            int excl = incl - sum;
            #pragma unroll
            for (int i2 = 0; i2 < 16; ++i2) {
                s_start[bse + i2] = excl + loc[i2];
                s_cur[bse + i2]   = excl + loc[i2];
            }
        }
        __syncthreads();                              // B3
        if (active) {
            int slot = atomicAdd(&s_cur[sb], 1);
            const uint4* vp = (const uint4*)(vb + (size_t)n * 8);
            uint4 v0 = vp[0], v1 = vp[1];
            unsigned* r = s_rec + slot * 12;
            *(uint4*)(r)     = v0;
            *(uint4*)(r + 4) = v1;
            float wx = cx ? c.x : 1.f - c.x;
            *(uint4*)(r + 8) = make_uint4(__float_as_uint(wx), __float_as_uint(c.y),
                                          __float_as_uint(c.z), 0u);
        }
        __syncthreads();                              // B4
        #pragma unroll
        for (int sy = 0; sy < 2; ++sy) {
            int yy = y - sy;
            if (yy < 0) continue;
            #pragma unroll
            for (int sz = 0; sz < 2; ++sz) {
                int zz = zc - sz;
                if (zz < 0) continue;
                int sbq = (yy << 5) | zz;
                int s = s_start[sbq], e = s + s_cnt[sbq];
                for (int i = s; i < e; ++i) {
                    const unsigned* r = s_rec + i * 12;
                    uint4 cw_ = *(const uint4*)(r + 8);
                    float wx = __uint_as_float(cw_.x);
                    float cy = __uint_as_float(cw_.y);
                    float cz = __uint_as_float(cw_.z);
                    float w = wx * (sy ? cy : 1.f - cy) * (sz ? cz : 1.f - cz);
                    uint4 u0 = *(const uint4*)(r);
                    uint4 u1 = *(const uint4*)(r + 4);
                    unsigned uu[8] = {u0.x, u0.y, u0.z, u0.w, u1.x, u1.y, u1.z, u1.w};
                    #pragma unroll
                    for (int q = 0; q < 8; ++q) {
                        float lo = __uint_as_float(uu[q] << 16);
                        float hi = __uint_as_float(uu[q] & 0xFFFF0000u);
                        acc[2 * q]     = fmaf(w, lo, acc[2 * q]);
                        acc[2 * q + 1] = fmaf(w, hi, acc[2 * q + 1]);
                    }
                }
            }
        }
        __syncthreads();                              // B5 (protect s_* before next zero)
    }
    unsigned int pk[8];
    #pragma unroll
    for (int q = 0; q < 8; ++q)
        pk[q] = (unsigned)f2bf(acc[2 * q]) | ((unsigned)f2bf(acc[2 * q + 1]) << 16);
    int pv = ((x0 + 1) * PS_ + y + 1) * PS_ + zc + 1;
    unsigned short* zb = zb16p + ((size_t)bh * PV_ + pv) * 16;
    ((uint4*)zb)[0] = make_uint4(pk[0], pk[1], pk[2], pk[3]);
    ((uint4*)zb)[1] = make_uint4(pk[4], pk[5], pk[6], pk[7]);
}

// ---------------- grouped 3x3x3 conv via bf16 MFMA, sliding y-window --------
__global__ __launch_bounds__(256) void conv3d_mfma(
    const unsigned short* __restrict__ zp, const unsigned short* __restrict__ wb,
    const float* __restrict__ cbias, unsigned short* __restrict__ zcb16) {
    int logical = (blockIdx.x & 7) * 128 + (blockIdx.x >> 3);  // 1024 = 8*128
    int bh = logical >> 5;
    int x  = logical & 31;
    int h = bh & 7;
    int lane = threadIdx.x & 63;
    int wv = threadIdx.x >> 6;
    int rc = lane & 15;
    int kb = lane >> 4;
    int ic0 = (kb & 1) << 3;
    int tsel = kb >> 1;
    int z0 = (wv & 1) << 4;
    int y0 = (wv >> 1) << 4;

    int aoff[5];
    #pragma unroll
    for (int pr = 0; pr < 5; ++pr) {
        int c = (pr < 4) ? (pr * 2 + tsel) : 8;
        int dx = c / 3, dz = c % 3;
        aoff[pr] = ((dx - 1) * PS2_ + (dz - 1)) * 32 + ic0 * 2;
    }
    bf16x8 bfr[15];
    const unsigned short* wh = wb + h * 30 * 256;
    #pragma unroll
    for (int p = 0; p < 15; ++p)
        bfr[p] = *(const bf16x8*)(wh + (((p * 2 + tsel) * 16 + rc) << 4) + ic0);
    float bias = cbias[h * 16 + rc];
    const char* zb = (const char*)(zp + (size_t)bh * PV_ * 16);
    unsigned short* zcb = zcb16 + ((size_t)bh << 19);
    int colbase = (x + 1) * PS2_ + z0 + rc + 1;

    bf16x8 w0[5], w1[5], w2[5];
    #pragma unroll
    for (int pr = 0; pr < 5; ++pr) {
        w0[pr] = *(const bf16x8*)(zb + (size_t)(colbase + (y0)     * PS_) * 32 + aoff[pr]);
        w1[pr] = *(const bf16x8*)(zb + (size_t)(colbase + (y0 + 1) * PS_) * 32 + aoff[pr]);
        w2[pr] = *(const bf16x8*)(zb + (size_t)(colbase + (y0 + 2) * PS_) * 32 + aoff[pr]);
    }
    #pragma unroll 1
    for (int y = y0; y < y0 + 16; ++y) {
        f32x4 a0 = {0.f, 0.f, 0.f, 0.f};
        f32x4 a1 = {0.f, 0.f, 0.f, 0.f};
        f32x4 a2 = {0.f, 0.f, 0.f, 0.f};
        #pragma unroll
        for (int pr = 0; pr < 5; ++pr) {
            a0 = __builtin_amdgcn_mfma_f32_16x16x32_bf16(w0[pr], bfr[pr],      a0, 0, 0, 0);
            a1 = __builtin_amdgcn_mfma_f32_16x16x32_bf16(w1[pr], bfr[5 + pr],  a1, 0, 0, 0);
            a2 = __builtin_amdgcn_mfma_f32_16x16x32_bf16(w2[pr], bfr[10 + pr], a2, 0, 0, 0);
        }
        int vout = (((x << 5) + y) << 5) + z0 + (kb << 2);
        #pragma unroll
        for (int r = 0; r < 4; ++r)
            zcb[(size_t)(vout + r) * 16 + rc] = f2bf(a0[r] + a1[r] + a2[r] + bias);
        #pragma unroll
        for (int pr = 0; pr < 5; ++pr) { w0[pr] = w1[pr]; w1[pr] = w2[pr]; }
        if (y < y0 + 15) {
            #pragma unroll
            for (int pr = 0; pr < 5; ++pr)
                w2[pr] = *(const bf16x8*)(zb + (size_t)(colbase + (y + 3) * PS_) * 32 + aoff[pr]);
        }
    }
}

// ---------------- slice: weighted gather + fused output stats ---------------
__global__ __launch_bounds__(256) void slice_vm(
    const unsigned short* __restrict__ zcb16, const float4* __restrict__ coordbuf,
    float* __restrict__ out, float* __restrict__ osum, float* __restrict__ osq) {
    __shared__ float s_sum[4][16], s_sq[4][16];
    int logical = (blockIdx.x & 7) * 128 + (blockIdx.x >> 3);  // 1024 = 8*128
    int tid = threadIdx.x;
    int p = logical * 256 + tid;
    int n = p & (N_ - 1);
    int bh = p >> 13;               // uniform per block
    int h = bh & 7, b = bh >> 3;
    float4 c = coordbuf[p];
    int pk = __float_as_int(c.w);
    int f0x = pk & 31, f0y = (pk >> 5) & 31, f0z = (pk >> 10) & 31;
    const unsigned short* gb = zcb16 + ((size_t)bh << 19);
    float acc[16];
    #pragma unroll
    for (int f = 0; f < 16; ++f) acc[f] = 0.f;
    #pragma unroll 1
    for (int k = 0; k < 8; ++k) {
        int cx = (k >> 2) & 1, cy = (k >> 1) & 1, cz = k & 1;
        float w = (cx ? c.x : 1.f - c.x) * (cy ? c.y : 1.f - c.y) * (cz ? c.z : 1.f - c.z);
        int vox = (((f0x + cx) << 5) + f0y + cy) * 32 + f0z + cz;
        const uint4* ip = (const uint4*)(gb + ((size_t)vox << 4));
        uint4 u0 = ip[0], u1 = ip[1];
        unsigned uu[8] = {u0.x, u0.y, u0.z, u0.w, u1.x, u1.y, u1.z, u1.w};
        #pragma unroll
        for (int q = 0; q < 8; ++q) {
            float lo = __uint_as_float(uu[q] << 16);
            float hi = __uint_as_float(uu[q] & 0xFFFF0000u);
            acc[2 * q]     = fmaf(w, lo, acc[2 * q]);
            acc[2 * q + 1] = fmaf(w, hi, acc[2 * q + 1]);
        }
    }
    #pragma unroll
    for (int f = 0; f < 16; ++f)
        out[(((size_t)(b * HF_ + h * F_ + f)) << 13) + n] = acc[f];
    float ps[16], pq[16];
    #pragma unroll
    for (int f = 0; f < 16; ++f) { ps[f] = acc[f]; pq[f] = acc[f] * acc[f]; }
    #pragma unroll
    for (int off = 1; off < 64; off <<= 1) {
        #pragma unroll
        for (int f = 0; f < 16; ++f) {
            ps[f] += __shfl_xor(ps[f], off);
            pq[f] += __shfl_xor(pq[f], off);
        }
    }
    int wv = tid >> 6;
    if ((tid & 63) == 0) {
        #pragma unroll
        for (int f = 0; f < 16; ++f) { s_sum[wv][f] = ps[f]; s_sq[wv][f] = pq[f]; }
    }
    __syncthreads();
    if (tid < 16) {
        float t = s_sum[0][tid] + s_sum[1][tid] + s_sum[2][tid] + s_sum[3][tid];
        float u = s_sq[0][tid] + s_sq[1][tid] + s_sq[2][tid] + s_sq[3][tid];
        atomicAdd(&osum[b * HF_ + h * F_ + tid], t);
        atomicAdd(&osq[b * HF_ + h * F_ + tid], u);
    }
}

// ---------------- final AdaIN + ReLU (stats from sums, in place) ------------
__global__ __launch_bounds__(256) void final_adain(
    float* __restrict__ out, const float* __restrict__ osum,
    const float* __restrict__ osq, const float* __restrict__ ha) {
    size_t i = (size_t)blockIdx.x * 256 + threadIdx.x;
    int bc = (int)(i >> 13);
    int c = bc & 127, b = bc >> 7;
    float mu = osum[bc] * INVN_;
    float rs = rsqrtf(osq[bc] * INVN_ - mu * mu + EPS_);
    float x = out[i];
    float xn = (x - mu) * rs;
    float y = fmaf(1.f + ha[b * 256 + c], xn, ha[b * 256 + 128 + c]);
    out[i] = fmaxf(y, 0.f);
}

extern "C" void kernel_launch(void* const* d_in, const int* in_sizes, int n_in,
                              void* d_out, int out_size, void* d_ws, size_t ws_size,
                              hipStream_t stream) {
    (void)in_sizes; (void)n_in; (void)out_size; (void)ws_size;
    const float* input   = (const float*)d_in[0];
    const float* style   = (const float*)d_in[1];
    const float* orig    = (const float*)d_in[2];
    const float* Wkv     = (const float*)d_in[3];
    const float* kw_w    = (const float*)d_in[4];
    const float* kw_b    = (const float*)d_in[5];
    const float* vw_w    = (const float*)d_in[6];
    const float* vw_b    = (const float*)d_in[7];
    const float* aw_w    = (const float*)d_in[8];
    const float* aw_b    = (const float*)d_in[9];
    const float* scale_p = (const float*)d_in[10];
    const float* Tw      = (const float*)d_in[11];
    const float* Tb      = (const float*)d_in[12];
    const float* conv_w  = (const float*)d_in[13];
    const float* conv_b  = (const float*)d_in[14];
    float* out = (float*)d_out;

    // -------- workspace layout (floats), ~146.0 MB total --------------------
    float* ws = (float*)d_ws;
    unsigned short* zb16p = (unsigned short*)ws;     // padded lattice bf16 (40.2MB)
    float* zc       = ws + 10061824;                 // 64MB region; conv uses first 32MB as bf16
    float* coordbuf = ws + 35227648;                 //  1,048,576
    float* wt       = ws + 36276224;                 //     55,296 floats (conv bf16 weights)
    float* wkb_f    = ws + 36331520;                 //     40,960 (W_kv bf16 frags)
    float* recs_f   = ws + 36372480;                 //    131,072 (262,144 u16)
    float* ha       = ws + 36503552;                 //      1,024
    float* hk       = ha + 1024;                     //        192
    float* hv       = hk + 192;                      //      1,024
    int*   counts   = (int*)(hv + 1024);             //      1,024 ints
    int*   cursor   = counts + 1024;                 //      1,024 ints
    float* sums     = (float*)(cursor + 1024);       //      2,240 floats (stat accumulators)
    float* kvsum    = sums;                          //        608
    float* kvsq     = kvsum + 608;                   //        608
    float* osum     = kvsq + 608;                    //        512
    float* osq      = osum + 512;                    //        512
    // aliased into zc region (dead before conv3d writes zcb16):
    unsigned* vbuf16 = (unsigned*)zc;                //  2,097,152 u32 (8MB) bf16 values
    float* kv   = zc + 2097152;                      //  4,980,736 (19MB)
    unsigned short* zcb16 = (unsigned short*)zc;     // conv output bf16 (32MB)
    unsigned short* wb16 = (unsigned short*)wt;
    unsigned short* wkb  = (unsigned short*)wkb_f;
    unsigned short* recs = (unsigned short*)recs_f;

    setup_misc<<<1102, 256, 0, stream>>>(style, kw_w, kw_b, vw_w, vw_b, aw_w, aw_b,
                                         conv_w, Wkv, hk, hv, ha, wb16, wkb,
                                         counts, cursor, sums, zb16p);
    kv_gemm_fused<<<dim3(64, B_), 256, 0, stream>>>(input, wkb, kv, kvsum, kvsq);
    point_prep<<<B_ * H_ * N_ / 256, 256, 0, stream>>>(
        kv, kvsum, kvsq, hk, hv, orig, scale_p, Tw, Tb,
        (float4*)coordbuf, vbuf16, counts);
    scatter_pts<<<B_ * H_ * N_ / 256, 256, 0, stream>>>(
        (const float4*)coordbuf, counts, cursor, recs);
    splat3<<<1024, 1024, 0, stream>>>((const float4*)coordbuf, vbuf16, counts, recs, zb16p);
    conv3d_mfma<<<1024, 256, 0, stream>>>(zb16p, wb16, conv_b, zcb16);
    slice_vm<<<B_ * H_ * N_ / 256, 256, 0, stream>>>(zcb16, (const float4*)coordbuf, out, osum, osq);
    final_adain<<<B_ * HF_ * N_ / 256, 256, 0, stream>>>(out, osum, osq, ha);
}

// Round 21
// 173.241 us; speedup vs baseline: 1.4724x; 1.4724x over previous
//
#include <hip/hip_runtime.h>
#include <hip/hip_bf16.h>
#include <math.h>

#define B_ 4
#define N_ 8192
#define MD_ 512
#define H_ 8
#define F_ 16
#define S_ 32
#define S3_ 32768
#define L_ 256
#define CO_ 152   // H*(F+3)
#define HF_ 128   // H*F
#define EPS_ 1e-5f
#define CHUNK_ 1024
#define PS_ 34            // padded lattice dim
#define PS2_ 1156         // 34*34
#define PV_ 39304         // 34^3 voxels per (b,h)
#define HALO_ 6536        // 34^3 - 32^3
#define INVN_ (1.f / 8192.f)

typedef __attribute__((ext_vector_type(8))) short bf16x8;
typedef __attribute__((ext_vector_type(4))) float f32x4;

__device__ inline unsigned short f2bf(float f) {   // RNE fp32 -> bf16
    unsigned u = __float_as_uint(f);
    return (unsigned short)((u + 0x7FFFu + ((u >> 16) & 1u)) >> 16);
}

// ---- fused setup: zeros + style_proj + conv-w + wconvert + halo + xconvert -
// xconvert via LDS transpose: block = 64 n x 512 c of one batch -> 64KB tile.
__global__ __launch_bounds__(256) void setup_misc(
    const float* __restrict__ style,
    const float* __restrict__ kw_w, const float* __restrict__ kw_b,
    const float* __restrict__ vw_w, const float* __restrict__ vw_b,
    const float* __restrict__ aw_w, const float* __restrict__ aw_b,
    const float* __restrict__ cw, const float* __restrict__ Wkv,
    const float* __restrict__ X,
    float* __restrict__ hk, float* __restrict__ hv, float* __restrict__ ha,
    unsigned short* __restrict__ wb, unsigned short* __restrict__ wkb,
    int* __restrict__ counts, int* __restrict__ cursor,
    float* __restrict__ sums, unsigned short* __restrict__ zb16p,
    unsigned short* __restrict__ xb) {
    __shared__ unsigned short s_x[32768];   // 64KB: [ntl(4)][kc(64)][nb(16)][k(8)]
    int blk = blockIdx.x;
    int tid = threadIdx.x;
    if (blk >= 1102) {                    // xconvert: 512 blocks
        int i = blk - 1102;               // b(4) x ng(128)
        int b  = i >> 7;
        int n0 = (i & 127) << 6;          // 64 n per block
        int r = tid >> 4;                 // 0..15  (c mod 16)
        int q = tid & 15;                 // n quad
        const float* xp = X + (size_t)b * MD_ * N_ + n0 + q * 4;
        #pragma unroll 4
        for (int it = 0; it < 32; ++it) {
            int c = r + (it << 4);
            float4 v = *(const float4*)(xp + (size_t)c * N_);
            int kc = c >> 3, k = c & 7;
            #pragma unroll
            for (int di = 0; di < 4; ++di) {
                int nl = q * 4 + di;
                float vv = (di == 0) ? v.x : (di == 1) ? v.y : (di == 2) ? v.z : v.w;
                s_x[(((nl >> 4) * 64 + kc) << 7) + ((nl & 15) << 3) + k] = f2bf(vv);
            }
        }
        __syncthreads();
        int nt0 = n0 >> 4;
        uint4* dst = (uint4*)(xb + (((size_t)(b * 512 + nt0)) * 64) * 128);
        const uint4* src = (const uint4*)s_x;
        #pragma unroll
        for (int w = 0; w < 16; ++w)
            dst[tid + (w << 8)] = src[tid + (w << 8)];
    } else if (blk == 0) {                // zero counters/cursors/stat sums
        #pragma unroll
        for (int q = 0; q < 4; ++q) counts[q * 256 + tid] = 0;
        #pragma unroll
        for (int q = 0; q < 4; ++q) cursor[q * 256 + tid] = 0;
        for (int i = tid; i < 2240; i += 256) sums[i] = 0.f;
    } else if (blk < 5) {                 // style projections (4 blocks)
        int b = blk - 1;
        const float* st = style + b * L_;
        for (int r = tid; r < 48 + 256 + 256; r += 256) {
            const float* wrow; float bias; float* dst; int j;
            if (r < 48)       { j = r;       wrow = kw_w + j * L_; bias = kw_b[j]; dst = hk + b * 48; }
            else if (r < 304) { j = r - 48;  wrow = vw_w + j * L_; bias = vw_b[j]; dst = hv + b * 256; }
            else              { j = r - 304; wrow = aw_w + j * L_; bias = aw_b[j]; dst = ha + b * 256; }
            float acc = bias;
            for (int l = 0; l < L_; ++l) acc = fmaf(st[l], wrow[l], acc);
            dst[j] = acc;
        }
    } else if (blk < 245) {               // conv weights, 61440 total
        int i = (blk - 5) * 256 + tid;
        if (i < 61440) {
            int ic = i & 15;
            int oc = (i >> 4) & 15;
            int s  = (i >> 8) % 30;
            int h  = (i >> 8) / 30;
            int p = s >> 1, tsel = s & 1;
            int pair = p % 5, dy = p / 5;
            int c = (pair < 4) ? (pair * 2 + tsel) : 8;
            bool zero = (pair == 4) && (tsel == 1);
            int tap = (c / 3) * 9 + dy * 3 + (c % 3);
            float v = zero ? 0.f : cw[(((h * 16 + oc) * 16 + ic) * 27) + tap];
            wb[i] = f2bf(v);
        }
    } else if (blk < 285) {               // W_kv -> bf16 frags [mt][kc][r16][k8]
        int i = (blk - 245) * 256 + tid;  // 10240 total
        if (i < 10240) {
            int r  = i & 15;
            int kc = (i >> 4) & 63;
            int mt = i >> 10;
            int row = mt * 16 + r;
            unsigned int pk[4];
            #pragma unroll
            for (int j = 0; j < 4; ++j) {
                float v0 = (row < CO_) ? Wkv[(size_t)row * MD_ + kc * 8 + 2 * j] : 0.f;
                float v1 = (row < CO_) ? Wkv[(size_t)row * MD_ + kc * 8 + 2 * j + 1] : 0.f;
                pk[j] = (unsigned)f2bf(v0) | ((unsigned)f2bf(v1) << 16);
            }
            *(uint4*)(wkb + (((size_t)(mt * 64 + kc)) * 16 + r) * 8) =
                make_uint4(pk[0], pk[1], pk[2], pk[3]);
        }
    } else {                              // halo zeroing: 817 blocks, 209152 = 32*HALO
        int i = (blk - 285) * 256 + tid;
        int bh = i / HALO_;
        int j  = i - bh * HALO_;
        int x, y, z;
        if (j < 2312) {
            x = (j / 1156) * 33;
            int rem = j % 1156;
            y = rem / 34; z = rem % 34;
        } else {
            int k = j - 2312;
            x = 1 + k / 132;
            int m = k % 132;
            if (m < 34)       { y = 0;  z = m; }
            else if (m < 68)  { y = 33; z = m - 34; }
            else if (m < 100) { y = m - 68 + 1;  z = 0; }
            else              { y = m - 100 + 1; z = 33; }
        }
        int pv = (x * PS_ + y) * PS_ + z;
        unsigned short* p = zb16p + ((size_t)bh * PV_ + pv) * 16;
        ((uint4*)p)[0] = make_uint4(0, 0, 0, 0);
        ((uint4*)p)[1] = make_uint4(0, 0, 0, 0);
    }
}

// ---------------- kv = W_kv @ input via bf16 MFMA + fused channel stats -----
__global__ __launch_bounds__(256) void kv_gemm_mfma(
    const unsigned short* __restrict__ xb, const unsigned short* __restrict__ wkb,
    float* __restrict__ kv, float* __restrict__ kvsum, float* __restrict__ kvsq) {
    int b  = blockIdx.z;
    int mt = blockIdx.y;
    int lane = threadIdx.x & 63, wv = threadIdx.x >> 6;
    int rc = lane & 15, kg = lane >> 4;
    int n0 = blockIdx.x * 512 + wv * 128;
    int nt0 = n0 >> 4;
    const unsigned short* ap = wkb + (((size_t)(mt * 64 + kg)) * 16 + rc) * 8;
    const unsigned short* bp = xb + ((((size_t)(b * 512 + nt0)) * 64 + kg) * 16 + rc) * 8;
    f32x4 acc[8];
    #pragma unroll
    for (int j = 0; j < 8; ++j) acc[j] = (f32x4){0.f, 0.f, 0.f, 0.f};
    #pragma unroll 1
    for (int ks = 0; ks < 16; ++ks) {
        bf16x8 a = *(const bf16x8*)(ap + ks * 512);
        #pragma unroll
        for (int j = 0; j < 8; ++j) {
            bf16x8 bfr = *(const bf16x8*)(bp + (size_t)j * 8192 + ks * 512);
            acc[j] = __builtin_amdgcn_mfma_f32_16x16x32_bf16(a, bfr, acc[j], 0, 0, 0);
        }
    }
    #pragma unroll
    for (int j = 0; j < 8; ++j) {
        int col = n0 + j * 16 + rc;
        #pragma unroll
        for (int r = 0; r < 4; ++r) {
            int m = mt * 16 + kg * 4 + r;
            if (m < CO_) kv[((size_t)b * CO_ + m) * N_ + col] = acc[j][r];
        }
    }
    #pragma unroll
    for (int r = 0; r < 4; ++r) {
        int m = mt * 16 + kg * 4 + r;
        float s = 0.f, q = 0.f;
        #pragma unroll
        for (int j = 0; j < 8; ++j) { float v = acc[j][r]; s += v; q = fmaf(v, v, q); }
        #pragma unroll
        for (int off = 1; off < 16; off <<= 1) {
            s += __shfl_xor(s, off);
            q += __shfl_xor(q, off);
        }
        if (rc == 0 && m < CO_) {
            atomicAdd(&kvsum[b * CO_ + m], s);
            atomicAdd(&kvsq[b * CO_ + m], q);
        }
    }
}

// ---------------- point prep: AdaIN (stats from sums) + transform + interp --
__global__ __launch_bounds__(256) void point_prep(
    const float* __restrict__ kv, const float* __restrict__ kvsum,
    const float* __restrict__ kvsq, const float* __restrict__ hk,
    const float* __restrict__ hv, const float* __restrict__ orig,
    const float* __restrict__ scale_p, const float* __restrict__ Tw,
    const float* __restrict__ Tb,
    float4* __restrict__ coordbuf, unsigned* __restrict__ vbuf16,
    int* __restrict__ counts) {
    __shared__ int s_hist[32];
    int tid = threadIdx.x;
    if (tid < 32) s_hist[tid] = 0;
    __syncthreads();
    int p = blockIdx.x * 256 + tid;
    int n = p & (N_ - 1);
    int bh = p >> 13;               // uniform per block
    int h = bh & 7, b = bh >> 3;
    float scl = scale_p[0];

    float pt[3];
    #pragma unroll
    for (int j = 0; j < 3; ++j) {
        int bc = b * CO_ + h * 3 + j;
        float mu = kvsum[bc] * INVN_;
        float rs = rsqrtf(kvsq[bc] * INVN_ - mu * mu + EPS_);
        float x  = kv[(size_t)bc * N_ + n];
        float xn = (x - mu) * rs;
        float kr = fmaf(1.f + hk[b * 48 + h * 3 + j], xn, hk[b * 48 + 24 + h * 3 + j]);
        pt[j] = fmaf(scl, kr, orig[((size_t)(b * 3 + j)) * N_ + n]);
    }
    int f0[3]; float tt[3];
    #pragma unroll
    for (int i = 0; i < 3; ++i) {
        float key = Tb[h * 3 + i];
        #pragma unroll
        for (int j = 0; j < 3; ++j) key = fmaf(Tw[(h * 3 + i) * 3 + j], pt[j], key);
        float lat = tanhf(key);
        float g = (lat + 1.f) * 0.5f * (float)(S_ - 1);
        float ff = floorf(g);
        ff = fminf(fmaxf(ff, 0.f), 30.f);
        f0[i] = (int)ff;
        tt[i] = fminf(fmaxf(g - ff, 0.f), 1.f);
    }
    coordbuf[p] = make_float4(tt[0], tt[1], tt[2],
                              __int_as_float(f0[0] | (f0[1] << 5) | (f0[2] << 10)));
    atomicAdd(&s_hist[f0[0]], 1);   // LDS
    float vf[16];
    #pragma unroll
    for (int f = 0; f < F_; ++f) {
        int bc = b * CO_ + 24 + h * F_ + f;
        float mu = kvsum[bc] * INVN_;
        float rs = rsqrtf(kvsq[bc] * INVN_ - mu * mu + EPS_);
        float x  = kv[(size_t)bc * N_ + n];
        float xn = (x - mu) * rs;
        int cv = h * F_ + f;
        vf[f] = fmaf(1.f + hv[b * 256 + cv], xn, hv[b * 256 + 128 + cv]);
    }
    unsigned pk2[8];
    #pragma unroll
    for (int q = 0; q < 8; ++q)
        pk2[q] = (unsigned)f2bf(vf[2 * q]) | ((unsigned)f2bf(vf[2 * q + 1]) << 16);
    uint4* vb = (uint4*)(vbuf16 + (size_t)p * 8);
    vb[0] = make_uint4(pk2[0], pk2[1], pk2[2], pk2[3]);
    vb[1] = make_uint4(pk2[4], pk2[5], pk2[6], pk2[7]);
    __syncthreads();
    if (tid < 32 && s_hist[tid] > 0)
        atomicAdd(&counts[(bh << 5) + tid], s_hist[tid]);
}

// ---------------- scatter: local prefix over counts + LDS-aggregated claim --
__global__ __launch_bounds__(256) void scatter_pts(
    const float4* __restrict__ coordbuf, const int* __restrict__ counts,
    int* __restrict__ cursor, unsigned short* __restrict__ recs) {
    __shared__ int s_hist[32];
    __shared__ int s_dst[32];
    int tid = threadIdx.x;
    if (tid < 32) s_hist[tid] = 0;
    __syncthreads();
    int p = blockIdx.x * 256 + tid;
    int bh = p >> 13;               // uniform per block
    int pk = __float_as_int(((const float*)coordbuf)[(size_t)p * 4 + 3]);
    int f0x = pk & 31;
    int rank = atomicAdd(&s_hist[f0x], 1);   // LDS
    __syncthreads();
    if (tid < 32) {
        int cnt = counts[(bh << 5) + tid];
        int incl = cnt;
        #pragma unroll
        for (int off = 1; off < 32; off <<= 1) {
            int u = __shfl_up(incl, off);
            if (tid >= off) incl += u;
        }
        int bse = (bh << 13) + incl - cnt;   // bh*8192 + exclusive prefix
        if (s_hist[tid] > 0)
            s_dst[tid] = bse + atomicAdd(&cursor[(bh << 5) + tid], s_hist[tid]);
    }
    __syncthreads();
    recs[s_dst[f0x] + rank] = (unsigned short)(p & (N_ - 1));
}

// ---------------- splat3 v3: CHUNK 1024, single-wave prefix, 5 barriers -----
__global__ __launch_bounds__(1024) void splat3(
    const float4* __restrict__ coordbuf, const unsigned* __restrict__ vbuf16,
    const int* __restrict__ counts, const unsigned short* __restrict__ recs,
    unsigned short* __restrict__ zb16p) {
    __shared__ int s_cnt[1024];
    __shared__ int s_start[1024];
    __shared__ int s_cur[1024];
    __shared__ unsigned s_rec[CHUNK_ * 12];   // 48KB sorted records
    __shared__ int s_binbase[33];
    int logical = (blockIdx.x & 7) * 128 + (blockIdx.x >> 3);  // XCD swizzle
    int bh = logical >> 5;
    int x0 = logical & 31;
    int tid = threadIdx.x;
    int y = tid >> 5, zc = tid & 31;
    if (tid < 32) {
        int cnt = counts[(bh << 5) + tid];
        int incl = cnt;
        #pragma unroll
        for (int off = 1; off < 32; off <<= 1) {
            int u = __shfl_up(incl, off);
            if (tid >= off) incl += u;
        }
        s_binbase[tid + 1] = incl;
        if (tid == 0) s_binbase[0] = 0;
    }
    __syncthreads();
    int s0 = (bh << 13) + s_binbase[x0];
    int len0 = s_binbase[x0 + 1] - s_binbase[x0];
    int s1 = 0, len1 = 0;
    if (x0 > 0) { s1 = (bh << 13) + s_binbase[x0 - 1]; len1 = s_binbase[x0] - s_binbase[x0 - 1]; }
    int total = len0 + len1;
    const float4* cb = coordbuf + (size_t)bh * N_;
    const unsigned* vb = vbuf16 + ((size_t)bh * N_) * 8;
    float acc[16];
    #pragma unroll
    for (int i = 0; i < 16; ++i) acc[i] = 0.f;

    for (int c0 = 0; c0 < total; c0 += CHUNK_) {
        int cl = min(CHUNK_, total - c0);
        s_cnt[tid] = 0;
        __syncthreads();                              // B1
        int n = 0, cx = 0, sb = 0;
        float4 c;
        bool active = (tid < cl);
        if (active) {
            int tp = c0 + tid;
            if (tp < len0) { n = recs[s0 + tp]; cx = 0; }
            else           { n = recs[s1 + (tp - len0)]; cx = 1; }
            c = cb[n];
            int pk = __float_as_int(c.w);
            sb = (((pk >> 5) & 31) << 5) | ((pk >> 10) & 31);
            atomicAdd(&s_cnt[sb], 1);
        }
        __syncthreads();                              // B2
        if (tid < 64) {                               // one wave scans all 1024 bins
            int bse = tid * 16;
            int loc[16], sum = 0;
            #pragma unroll
            for (int i2 = 0; i2 < 16; ++i2) { loc[i2] = sum; sum += s_cnt[bse + i2]; }
            int incl = sum;
            #pragma unroll
            for (int off = 1; off < 64; off <<= 1) {
                int u = __shfl_up(incl, off);
                if (tid >= off) incl += u;
            }
            int excl = incl - sum;
            #pragma unroll
            for (int i2 = 0; i2 < 16; ++i2) {
                s_start[bse + i2] = excl + loc[i2];
                s_cur[bse + i2]   = excl + loc[i2];
            }
        }
        __syncthreads();                              // B3
        if (active) {
            int slot = atomicAdd(&s_cur[sb], 1);
            const uint4* vp = (const uint4*)(vb + (size_t)n * 8);
            uint4 v0 = vp[0], v1 = vp[1];
            unsigned* r = s_rec + slot * 12;
            *(uint4*)(r)     = v0;
            *(uint4*)(r + 4) = v1;
            float wx = cx ? c.x : 1.f - c.x;
            *(uint4*)(r + 8) = make_uint4(__float_as_uint(wx), __float_as_uint(c.y),
                                          __float_as_uint(c.z), 0u);
        }
        __syncthreads();                              // B4
        #pragma unroll
        for (int sy = 0; sy < 2; ++sy) {
            int yy = y - sy;
            if (yy < 0) continue;
            #pragma unroll
            for (int sz = 0; sz < 2; ++sz) {
                int zz = zc - sz;
                if (zz < 0) continue;
                int sbq = (yy << 5) | zz;
                int s = s_start[sbq], e = s + s_cnt[sbq];
                for (int i = s; i < e; ++i) {
                    const unsigned* r = s_rec + i * 12;
                    uint4 cw_ = *(const uint4*)(r + 8);
                    float wx = __uint_as_float(cw_.x);
                    float cy = __uint_as_float(cw_.y);
                    float cz = __uint_as_float(cw_.z);
                    float w = wx * (sy ? cy : 1.f - cy) * (sz ? cz : 1.f - cz);
                    uint4 u0 = *(const uint4*)(r);
                    uint4 u1 = *(const uint4*)(r + 4);
                    unsigned uu[8] = {u0.x, u0.y, u0.z, u0.w, u1.x, u1.y, u1.z, u1.w};
                    #pragma unroll
                    for (int q = 0; q < 8; ++q) {
                        float lo = __uint_as_float(uu[q] << 16);
                        float hi = __uint_as_float(uu[q] & 0xFFFF0000u);
                        acc[2 * q]     = fmaf(w, lo, acc[2 * q]);
                        acc[2 * q + 1] = fmaf(w, hi, acc[2 * q + 1]);
                    }
                }
            }
        }
        __syncthreads();                              // B5 (protect s_* before next zero)
    }
    unsigned int pk[8];
    #pragma unroll
    for (int q = 0; q < 8; ++q)
        pk[q] = (unsigned)f2bf(acc[2 * q]) | ((unsigned)f2bf(acc[2 * q + 1]) << 16);
    int pv = ((x0 + 1) * PS_ + y + 1) * PS_ + zc + 1;
    unsigned short* zb = zb16p + ((size_t)bh * PV_ + pv) * 16;
    ((uint4*)zb)[0] = make_uint4(pk[0], pk[1], pk[2], pk[3]);
    ((uint4*)zb)[1] = make_uint4(pk[4], pk[5], pk[6], pk[7]);
}

// ---------------- grouped 3x3x3 conv via bf16 MFMA, sliding y-window --------
__global__ __launch_bounds__(256) void conv3d_mfma(
    const unsigned short* __restrict__ zp, const unsigned short* __restrict__ wb,
    const float* __restrict__ cbias, unsigned short* __restrict__ zcb16) {
    int logical = (blockIdx.x & 7) * 128 + (blockIdx.x >> 3);  // 1024 = 8*128
    int bh = logical >> 5;
    int x  = logical & 31;
    int h = bh & 7;
    int lane = threadIdx.x & 63;
    int wv = threadIdx.x >> 6;
    int rc = lane & 15;
    int kb = lane >> 4;
    int ic0 = (kb & 1) << 3;
    int tsel = kb >> 1;
    int z0 = (wv & 1) << 4;
    int y0 = (wv >> 1) << 4;

    int aoff[5];
    #pragma unroll
    for (int pr = 0; pr < 5; ++pr) {
        int c = (pr < 4) ? (pr * 2 + tsel) : 8;
        int dx = c / 3, dz = c % 3;
        aoff[pr] = ((dx - 1) * PS2_ + (dz - 1)) * 32 + ic0 * 2;
    }
    bf16x8 bfr[15];
    const unsigned short* wh = wb + h * 30 * 256;
    #pragma unroll
    for (int p = 0; p < 15; ++p)
        bfr[p] = *(const bf16x8*)(wh + (((p * 2 + tsel) * 16 + rc) << 4) + ic0);
    float bias = cbias[h * 16 + rc];
    const char* zb = (const char*)(zp + (size_t)bh * PV_ * 16);
    unsigned short* zcb = zcb16 + ((size_t)bh << 19);
    int colbase = (x + 1) * PS2_ + z0 + rc + 1;

    bf16x8 w0[5], w1[5], w2[5];
    #pragma unroll
    for (int pr = 0; pr < 5; ++pr) {
        w0[pr] = *(const bf16x8*)(zb + (size_t)(colbase + (y0)     * PS_) * 32 + aoff[pr]);
        w1[pr] = *(const bf16x8*)(zb + (size_t)(colbase + (y0 + 1) * PS_) * 32 + aoff[pr]);
        w2[pr] = *(const bf16x8*)(zb + (size_t)(colbase + (y0 + 2) * PS_) * 32 + aoff[pr]);
    }
    #pragma unroll 1
    for (int y = y0; y < y0 + 16; ++y) {
        f32x4 a0 = {0.f, 0.f, 0.f, 0.f};
        f32x4 a1 = {0.f, 0.f, 0.f, 0.f};
        f32x4 a2 = {0.f, 0.f, 0.f, 0.f};
        #pragma unroll
        for (int pr = 0; pr < 5; ++pr) {
            a0 = __builtin_amdgcn_mfma_f32_16x16x32_bf16(w0[pr], bfr[pr],      a0, 0, 0, 0);
            a1 = __builtin_amdgcn_mfma_f32_16x16x32_bf16(w1[pr], bfr[5 + pr],  a1, 0, 0, 0);
            a2 = __builtin_amdgcn_mfma_f32_16x16x32_bf16(w2[pr], bfr[10 + pr], a2, 0, 0, 0);
        }
        int vout = (((x << 5) + y) << 5) + z0 + (kb << 2);
        #pragma unroll
        for (int r = 0; r < 4; ++r)
            zcb[(size_t)(vout + r) * 16 + rc] = f2bf(a0[r] + a1[r] + a2[r] + bias);
        #pragma unroll
        for (int pr = 0; pr < 5; ++pr) { w0[pr] = w1[pr]; w1[pr] = w2[pr]; }
        if (y < y0 + 15) {
            #pragma unroll
            for (int pr = 0; pr < 5; ++pr)
                w2[pr] = *(const bf16x8*)(zb + (size_t)(colbase + (y + 3) * PS_) * 32 + aoff[pr]);
        }
    }
}

// ---------------- slice: weighted gather + fused output stats ---------------
__global__ __launch_bounds__(256) void slice_vm(
    const unsigned short* __restrict__ zcb16, const float4* __restrict__ coordbuf,
    float* __restrict__ out, float* __restrict__ osum, float* __restrict__ osq) {
    __shared__ float s_sum[4][16], s_sq[4][16];
    int logical = (blockIdx.x & 7) * 128 + (blockIdx.x >> 3);  // 1024 = 8*128
    int tid = threadIdx.x;
    int p = logical * 256 + tid;
    int n = p & (N_ - 1);
    int bh = p >> 13;               // uniform per block
    int h = bh & 7, b = bh >> 3;
    float4 c = coordbuf[p];
    int pk = __float_as_int(c.w);
    int f0x = pk & 31, f0y = (pk >> 5) & 31, f0z = (pk >> 10) & 31;
    const unsigned short* gb = zcb16 + ((size_t)bh << 19);
    float acc[16];
    #pragma unroll
    for (int f = 0; f < 16; ++f) acc[f] = 0.f;
    #pragma unroll 1
    for (int k = 0; k < 8; ++k) {
        int cx = (k >> 2) & 1, cy = (k >> 1) & 1, cz = k & 1;
        float w = (cx ? c.x : 1.f - c.x) * (cy ? c.y : 1.f - c.y) * (cz ? c.z : 1.f - c.z);
        int vox = (((f0x + cx) << 5) + f0y + cy) * 32 + f0z + cz;
        const uint4* ip = (const uint4*)(gb + ((size_t)vox << 4));
        uint4 u0 = ip[0], u1 = ip[1];
        unsigned uu[8] = {u0.x, u0.y, u0.z, u0.w, u1.x, u1.y, u1.z, u1.w};
        #pragma unroll
        for (int q = 0; q < 8; ++q) {
            float lo = __uint_as_float(uu[q] << 16);
            float hi = __uint_as_float(uu[q] & 0xFFFF0000u);
            acc[2 * q]     = fmaf(w, lo, acc[2 * q]);
            acc[2 * q + 1] = fmaf(w, hi, acc[2 * q + 1]);
        }
    }
    #pragma unroll
    for (int f = 0; f < 16; ++f)
        out[(((size_t)(b * HF_ + h * F_ + f)) << 13) + n] = acc[f];
    float ps[16], pq[16];
    #pragma unroll
    for (int f = 0; f < 16; ++f) { ps[f] = acc[f]; pq[f] = acc[f] * acc[f]; }
    #pragma unroll
    for (int off = 1; off < 64; off <<= 1) {
        #pragma unroll
        for (int f = 0; f < 16; ++f) {
            ps[f] += __shfl_xor(ps[f], off);
            pq[f] += __shfl_xor(pq[f], off);
        }
    }
    int wv = tid >> 6;
    if ((tid & 63) == 0) {
        #pragma unroll
        for (int f = 0; f < 16; ++f) { s_sum[wv][f] = ps[f]; s_sq[wv][f] = pq[f]; }
    }
    __syncthreads();
    if (tid < 16) {
        float t = s_sum[0][tid] + s_sum[1][tid] + s_sum[2][tid] + s_sum[3][tid];
        float u = s_sq[0][tid] + s_sq[1][tid] + s_sq[2][tid] + s_sq[3][tid];
        atomicAdd(&osum[b * HF_ + h * F_ + tid], t);
        atomicAdd(&osq[b * HF_ + h * F_ + tid], u);
    }
}

// ---------------- final AdaIN + ReLU (stats from sums, in place) ------------
__global__ __launch_bounds__(256) void final_adain(
    float* __restrict__ out, const float* __restrict__ osum,
    const float* __restrict__ osq, const float* __restrict__ ha) {
    size_t i = (size_t)blockIdx.x * 256 + threadIdx.x;
    int bc = (int)(i >> 13);
    int c = bc & 127, b = bc >> 7;
    float mu = osum[bc] * INVN_;
    float rs = rsqrtf(osq[bc] * INVN_ - mu * mu + EPS_);
    float x = out[i];
    float xn = (x - mu) * rs;
    float y = fmaf(1.f + ha[b * 256 + c], xn, ha[b * 256 + 128 + c]);
    out[i] = fmaxf(y, 0.f);
}

extern "C" void kernel_launch(void* const* d_in, const int* in_sizes, int n_in,
                              void* d_out, int out_size, void* d_ws, size_t ws_size,
                              hipStream_t stream) {
    (void)in_sizes; (void)n_in; (void)out_size; (void)ws_size;
    const float* input   = (const float*)d_in[0];
    const float* style   = (const float*)d_in[1];
    const float* orig    = (const float*)d_in[2];
    const float* Wkv     = (const float*)d_in[3];
    const float* kw_w    = (const float*)d_in[4];
    const float* kw_b    = (const float*)d_in[5];
    const float* vw_w    = (const float*)d_in[6];
    const float* vw_b    = (const float*)d_in[7];
    const float* aw_w    = (const float*)d_in[8];
    const float* aw_b    = (const float*)d_in[9];
    const float* scale_p = (const float*)d_in[10];
    const float* Tw      = (const float*)d_in[11];
    const float* Tb      = (const float*)d_in[12];
    const float* conv_w  = (const float*)d_in[13];
    const float* conv_b  = (const float*)d_in[14];
    float* out = (float*)d_out;

    // -------- workspace layout (floats), ~146.0 MB total --------------------
    float* ws = (float*)d_ws;
    unsigned short* zb16p = (unsigned short*)ws;     // padded lattice bf16 (40.2MB)
    float* zc       = ws + 10061824;                 // 64MB region; conv uses first 32MB as bf16
    float* xbf_f    = ws + 26839040;                 //  8,388,608 (32MB) bf16 input frags
    float* coordbuf = ws + 35227648;                 //  1,048,576
    float* wt       = ws + 36276224;                 //     55,296 floats (conv bf16 weights)
    float* wkb_f    = ws + 36331520;                 //     40,960 (W_kv bf16 frags)
    float* recs_f   = ws + 36372480;                 //    131,072 (262,144 u16)
    float* ha       = ws + 36503552;                 //      1,024
    float* hk       = ha + 1024;                     //        192
    float* hv       = hk + 192;                      //      1,024
    int*   counts   = (int*)(hv + 1024);             //      1,024 ints
    int*   cursor   = counts + 1024;                 //      1,024 ints
    float* sums     = (float*)(cursor + 1024);       //      2,240 floats (stat accumulators)
    float* kvsum    = sums;                          //        608
    float* kvsq     = kvsum + 608;                   //        608
    float* osum     = kvsq + 608;                    //        512
    float* osq      = osum + 512;                    //        512
    // aliased into zc region (dead before conv3d writes zcb16):
    unsigned* vbuf16 = (unsigned*)zc;                //  2,097,152 u32 (8MB) bf16 values
    float* kv   = zc + 2097152;                      //  4,980,736 (19MB)
    unsigned short* zcb16 = (unsigned short*)zc;     // conv output bf16 (32MB)
    unsigned short* xbf  = (unsigned short*)xbf_f;
    unsigned short* wb16 = (unsigned short*)wt;
    unsigned short* wkb  = (unsigned short*)wkb_f;
    unsigned short* recs = (unsigned short*)recs_f;

    setup_misc<<<1614, 256, 0, stream>>>(style, kw_w, kw_b, vw_w, vw_b, aw_w, aw_b,
                                         conv_w, Wkv, input, hk, hv, ha, wb16, wkb,
                                         counts, cursor, sums, zb16p, xbf);
    kv_gemm_mfma<<<dim3(16, 10, B_), 256, 0, stream>>>(xbf, wkb, kv, kvsum, kvsq);
    point_prep<<<B_ * H_ * N_ / 256, 256, 0, stream>>>(
        kv, kvsum, kvsq, hk, hv, orig, scale_p, Tw, Tb,
        (float4*)coordbuf, vbuf16, counts);
    scatter_pts<<<B_ * H_ * N_ / 256, 256, 0, stream>>>(
        (const float4*)coordbuf, counts, cursor, recs);
    splat3<<<1024, 1024, 0, stream>>>((const float4*)coordbuf, vbuf16, counts, recs, zb16p);
    conv3d_mfma<<<1024, 256, 0, stream>>>(zb16p, wb16, conv_b, zcb16);
    slice_vm<<<B_ * H_ * N_ / 256, 256, 0, stream>>>(zcb16, (const float4*)coordbuf, out, osum, osq);
    final_adain<<<B_ * HF_ * N_ / 256, 256, 0, stream>>>(out, osum, osq, ha);
}